// Round 11
// baseline (113.851 us; speedup 1.0000x reference)
//
#include <hip/hip_runtime.h>

// Fused iterated 3x3 median blur (edge-replicate), up to 9 iterations.
// R7 structure (the measured optimum): 64x64 output tile + 9 halo = 82x82
// LDS (26.9 KB), 256 threads, each owning a contiguous 5x5 patch of compute
// region [1,80]^2 in registers; 24 ring reads + 16 ring writes per iter.
// R11 deltas vs R7: (1) IN-PLACE row sweep (stage row i last consumed at
// step i-1 -> step i may overwrite it; kills the ns[25] buffer and 25
// copies/iter) with NO forced min-wave bound; (2) batch-fastest dispatch
// interleave (b = blockIdx.x & 31) to mix per-batch T through the dispatch
// stream and shrink the makespan tail. Valid-after-k = [k,81-k]; after 9
// iters = [9,72] = exactly the output tile. Image-edge replicate pads are
// register fixups (row fix then col fix -> corners exact).

#define TD 82
#define OW 64
#define RAD 9
#define NT 256

__device__ __forceinline__ float min3f(float a, float b, float c) { return fminf(fminf(a, b), c); }
__device__ __forceinline__ float max3f(float a, float b, float c) { return fmaxf(fmaxf(a, b), c); }
__device__ __forceinline__ float med3f(float a, float b, float c) { return __builtin_amdgcn_fmed3f(a, b, c); }

__global__ __launch_bounds__(NT) void median_fused_kernel(
    const float* __restrict__ src, float* __restrict__ dst,
    const int* __restrict__ t)
{
    __shared__ float buf[TD * TD];

    const int b    = blockIdx.x & 31;         // batch fastest: interleave T
    const int tile = blockIdx.x >> 5;         // 0..63 (8x8 tiles of 64)
    const int y0   = (tile >> 3) * OW;
    const int x0   = (tile & 7) * OW;
    const int tid  = threadIdx.x;
    const float* img  = src + (b << 18);
    float*       outb = dst + (b << 18);

    int T = t[b];
    T = min(max(T, 0), 9);

    const int sr = tid >> 4;            // store: 16 row groups x 4
    const int sc = (tid & 15) << 2;     // store: 16 x float4

    if (T == 0) {                       // straight vector copy, no LDS
        #pragma unroll
        for (int rr = 0; rr < 4; ++rr) {
            int gy = y0 + sr + rr * 16;
            *(float4*)&outb[(gy << 9) + x0 + sc] =
                *(const float4*)&img[(gy << 9) + x0 + sc];
        }
        return;
    }

    // ---- load 82x82 halo tile, clamped (= replicate-padded image) ----
    for (int i = tid; i < TD * TD; i += NT) {
        int r = i / TD, c = i - r * TD;
        int gy = min(max(y0 - RAD + r, 0), 511);
        int gx = min(max(x0 - RAD + c, 0), 511);
        buf[i] = img[(gy << 9) + gx];
    }

    const bool topE = (y0 == 0), botE = (y0 == 512 - OW);
    const bool lftE = (x0 == 0), rgtE = (x0 == 512 - OW);

    const int ptx = tid & 15;           // 16 col groups x 5
    const int pty = tid >> 4;           // 16 row groups x 5
    const int ub  = 1 + 5 * pty;        // patch rows [ub, ub+4]
    const int vb  = 1 + 5 * ptx;        // patch cols [vb, vb+4]

    // pad roles: image row 0 = tile row 9 = pty==1 i=3 (pad row 8 = i=2);
    // image row 511 = tile row 72 = pty==14 i=1 (pad row 73 = i=2). Cols sym.
    const bool padTop = topE && (pty == 1);
    const bool padBot = botE && (pty == 14);
    const bool padLft = lftE && (ptx == 1);
    const bool padRgt = rgtE && (ptx == 14);

    __syncthreads();

    // preload own 5x5 patch (state 0) into registers
    float stage[25];
    #pragma unroll
    for (int i = 0; i < 5; ++i)
        #pragma unroll
        for (int j = 0; j < 5; ++j)
            stage[i * 5 + j] = buf[(ub + i) * TD + vb + j];

    for (int k = 0; k < T; ++k) {
        float A[7], Bx[7], C[7];
        // window row ub-1: all 7 from LDS (neighbor ring)
        {
            const float* p = &buf[(ub - 1) * TD + (vb - 1)];
            #pragma unroll
            for (int j = 0; j < 7; ++j) A[j] = p[j];
        }
        // window row ub: edges from LDS, middle from stage row 0
        Bx[0] = buf[ub * TD + (vb - 1)];
        #pragma unroll
        for (int j = 0; j < 5; ++j) Bx[1 + j] = stage[j];
        Bx[6] = buf[ub * TD + (vb + 5)];

        #pragma unroll
        for (int i = 0; i < 5; ++i) {
            if (i < 4) {                // rows ub+1..ub+4: edges LDS, mid regs
                C[0] = buf[(ub + 1 + i) * TD + (vb - 1)];
                #pragma unroll
                for (int j = 0; j < 5; ++j) C[1 + j] = stage[(i + 1) * 5 + j];
                C[6] = buf[(ub + 1 + i) * TD + (vb + 5)];
            } else {                    // row ub+5: all 7 from LDS
                const float* q = &buf[(ub + 5) * TD + (vb - 1)];
                #pragma unroll
                for (int j = 0; j < 7; ++j) C[j] = q[j];
            }
            float lo[7], mi[7], hi[7];
            #pragma unroll
            for (int j = 0; j < 7; ++j) {
                lo[j] = min3f(A[j], Bx[j], C[j]);
                mi[j] = med3f(A[j], Bx[j], C[j]);
                hi[j] = max3f(A[j], Bx[j], C[j]);
            }
            // in-place: stage row i was last consumed at step i-1
            #pragma unroll
            for (int j = 0; j < 5; ++j)
                stage[i * 5 + j] = med3f(max3f(lo[j], lo[j+1], lo[j+2]),
                                         med3f(mi[j], mi[j+1], mi[j+2]),
                                         min3f(hi[j], hi[j+1], hi[j+2]));
            #pragma unroll
            for (int j = 0; j < 7; ++j) { A[j] = Bx[j]; Bx[j] = C[j]; }
        }

        // register pad fixups (row fix first, then col -> corners exact)
        if (padTop) {                   // pad row 8 (i=2) <- new row 9 (i=3)
            #pragma unroll
            for (int j = 0; j < 5; ++j) stage[10 + j] = stage[15 + j];
        }
        if (padBot) {                   // pad row 73 (i=2) <- new row 72 (i=1)
            #pragma unroll
            for (int j = 0; j < 5; ++j) stage[10 + j] = stage[5 + j];
        }
        if (padLft) {                   // pad col 8 (j=2) <- new col 9 (j=3)
            #pragma unroll
            for (int i = 0; i < 5; ++i) stage[i * 5 + 2] = stage[i * 5 + 3];
        }
        if (padRgt) {                   // pad col 73 (j=2) <- new col 72 (j=1)
            #pragma unroll
            for (int i = 0; i < 5; ++i) stage[i * 5 + 2] = stage[i * 5 + 1];
        }

        __syncthreads();                // all ring reads of state k done

        if (k == T - 1) {               // final: write all 25 for store phase
            #pragma unroll
            for (int i = 0; i < 5; ++i)
                #pragma unroll
                for (int j = 0; j < 5; ++j)
                    buf[(ub + i) * TD + vb + j] = stage[i * 5 + j];
        } else {                        // write the 16-cell patch ring only
            #pragma unroll
            for (int j = 0; j < 5; ++j) buf[ub * TD + vb + j]       = stage[j];
            #pragma unroll
            for (int j = 0; j < 5; ++j) buf[(ub + 4) * TD + vb + j] = stage[20 + j];
            #pragma unroll
            for (int i = 1; i < 4; ++i) {
                buf[(ub + i) * TD + vb]     = stage[i * 5];
                buf[(ub + i) * TD + vb + 4] = stage[i * 5 + 4];
            }
        }

        __syncthreads();                // new ring visible
    }

    // ---- store 64x64 output tile, float4 global stores ----
    #pragma unroll
    for (int rr = 0; rr < 4; ++rr) {
        int row = sr + rr * 16;
        const float* s = &buf[(row + RAD) * TD + RAD + sc];
        float4 v = { s[0], s[1], s[2], s[3] };
        *(float4*)&outb[((y0 + row) << 9) + x0 + sc] = v;
    }
}

extern "C" void kernel_launch(void* const* d_in, const int* in_sizes, int n_in,
                              void* d_out, int out_size, void* d_ws, size_t ws_size,
                              hipStream_t stream) {
    const float* x   = (const float*)d_in[0];
    const int*   t   = (const int*)d_in[1];
    float*       out = (float*)d_out;

    dim3 block(NT);
    dim3 grid(2048);   // 64 tiles x 32 batches, batch-fastest interleave
    median_fused_kernel<<<grid, block, 0, stream>>>(x, out, t);
}